// Round 8
// baseline (96.162 us; speedup 1.0000x reference)
//
#include <hip/hip_runtime.h>

#define BB 8
#define NN 4096
#define CCH 512
#define KK 32
#define CLS 21
#define BN_EPS 1e-3f

#define TPB 1024
#define CHUNK 64
#define NBLK (NN / CHUNK)   // 64 -> grid (64,8) = 512 blocks = 2/CU, 32 waves/CU

typedef _Float16 f16;
typedef _Float16 f16x4 __attribute__((ext_vector_type(4)));
typedef _Float16 f16x8 __attribute__((ext_vector_type(8)));
typedef float f32x4 __attribute__((ext_vector_type(4)));

#define NP 36    // wtT row pitch in f16

// LDS carve (bytes)
#define LB_CWB  0                         // f16[2][16][64][8]            32768
#define LB_RED  32768                     // f32[2tl][6][64][4]           12288
#define LB_WTT  45056                     // f16[2tl][32][NP]              4608
#define LB_XSQ  49664                     // f32[2tl][4][16]                512
#define LB_CSQ  50176                     // f32[32]                        128
#define LB_NSF  50304                     // f32[32]                        128
#define LB_WSQ  50432                     // f32[2tl][4][16]                512
#define LB_TOT  50944
#define LB_ACC  0                         // epilogue scratch aliases cwB (dead): 32768

// ws layout (floats)
#define WS_P    0                                  // [NBLK][BB][CCH][KK]
#define WS_WSP  (NBLK * BB * CCH * KK)             // 8388608
#define WS_ENC  (WS_WSP + NBLK * BB * KK)          // 8404992
#define WS_ATTN (WS_ENC + BB * CCH)                // 8409088
#define WS_END  (WS_ATTN + BB * CCH)

template <int CTRL>
__device__ __forceinline__ float dpp_add(float v) {
    int r = __builtin_amdgcn_update_dpp(0, __builtin_bit_cast(int, v),
                                        CTRL, 0xF, 0xF, true);
    return v + __builtin_bit_cast(float, r);
}
template <int CTRL>
__device__ __forceinline__ float dpp_max(float v) {
    int r = __builtin_amdgcn_update_dpp(0, __builtin_bit_cast(int, v),
                                        CTRL, 0xF, 0xF, true);
    return fmaxf(v, __builtin_bit_cast(float, r));
}
__device__ __forceinline__ float rowsum16(float v) {
    v = dpp_add<0x128>(v); v = dpp_add<0x124>(v);
    v = dpp_add<0x122>(v); v = dpp_add<0x121>(v);
    return v;
}
__device__ __forceinline__ float rowmax16(float v) {
    v = dpp_max<0x128>(v); v = dpp_max<0x124>(v);
    v = dpp_max<0x122>(v); v = dpp_max<0x121>(v);
    return v;
}

// ---------------------------------------------------------------------------
// Kernel A (MFMA, 16 waves): waves tl*8+wi; tile tl (32 rows), roles within
// tile: m=wi&1, kt=(wi>>1)&1, ch=wi>>2.  Both tiles run concurrently between
// the same barriers -> 2x loads in flight vs r7.  Epilogue sums tl pairs via
// LDS (aliasing dead cwB) in 2 rounds, then streams partials (layout as r7).
// ---------------------------------------------------------------------------
__global__ __launch_bounds__(TPB, 2) void enc_mfma(
    const float* __restrict__ x, const float* __restrict__ cw,
    const float* __restrict__ sf, float* __restrict__ ws)
{
    extern __shared__ char sm[];
    f16*   cwB  = (f16*)(sm + LB_CWB);
    float* red  = (float*)(sm + LB_RED);
    f16*   wtT  = (f16*)(sm + LB_WTT);
    float* xsq  = (float*)(sm + LB_XSQ);
    float* csqL = (float*)(sm + LB_CSQ);
    float* nsfL = (float*)(sm + LB_NSF);
    float* wsq  = (float*)(sm + LB_WSQ);

    const int t = threadIdx.x;
    const int b = blockIdx.y;
    const int w  = t >> 6;
    const int tl = w >> 3;          // tile 0/1
    const int wi = w & 7;           // role within tile
    const int l = t & 63;
    const int a = l & 15;
    const int g = l >> 4;

    // ---- stage cwB in B-fragment layout (once per block; 2048 slots, 1024 thr) ----
    for (int si = 0; si < 2; ++si) {
        const int s     = si * 1024 + t;       // 0..2047
        const int lane  = s & 63;
        const int cstep = (s >> 6) & 15;
        const int kt    = s >> 10;
        const int k     = (lane & 15) + 16 * kt;
        const int c0    = cstep * 32 + (lane >> 4) * 8;
        f16x8 v;
#pragma unroll
        for (int i = 0; i < 8; ++i) v[i] = (f16)cw[(c0 + i) * KK + k];
        *reinterpret_cast<f16x8*>(cwB + ((size_t)(kt * 16 + cstep) * 64 + lane) * 8) = v;
    }
    // ---- cwsq partials (red used as scratch) ----
    if (t < 256) {
        const int k = t & 31, part = t >> 5;
        float sacc = 0.f;
        for (int c = part * 64; c < part * 64 + 64; ++c) {
            const float v = cw[c * KK + k];
            sacc += v * v;
        }
        red[part * 32 + k] = sacc;
    }
    __syncthreads();
    if (t < 32) {
        float sacc = 0.f;
#pragma unroll
        for (int p = 0; p < 8; ++p) sacc += red[p * 32 + t];
        csqL[t] = sacc;
        nsfL[t] = -sf[t];
    }
    __syncthreads();

    const int m_  = wi & 1;
    const int kt_ = (wi >> 1) & 1;
    const int ch_ = wi >> 2;
    const int n0  = blockIdx.x * CHUNK + tl * 32;

    f32x4 acc[4][2];
#pragma unroll
    for (int ct = 0; ct < 4; ++ct)
#pragma unroll
        for (int kt = 0; kt < 2; ++kt) acc[ct][kt] = (f32x4){0.f, 0.f, 0.f, 0.f};

    // ---- cross MFMA: A-frags from global, B-frags from cwB ----
    f32x4 d = {0.f, 0.f, 0.f, 0.f};
    {
        float sq = 0.f;
        const float* xrow = x + (size_t)(b * NN + n0 + 16 * m_ + a) * CCH;
#pragma unroll
        for (int cs = 0; cs < 8; ++cs) {
            const int cstep = ch_ * 8 + cs;
            const int c0 = cstep * 32 + g * 8;
            const float4 u0 = *reinterpret_cast<const float4*>(xrow + c0);
            const float4 u1 = *reinterpret_cast<const float4*>(xrow + c0 + 4);
            if (kt_ == 0)
                sq += u0.x*u0.x + u0.y*u0.y + u0.z*u0.z + u0.w*u0.w
                    + u1.x*u1.x + u1.y*u1.y + u1.z*u1.z + u1.w*u1.w;
            const f16x8 af = {(f16)u0.x, (f16)u0.y, (f16)u0.z, (f16)u0.w,
                              (f16)u1.x, (f16)u1.y, (f16)u1.z, (f16)u1.w};
            const f16x8 bf = *reinterpret_cast<const f16x8*>(
                cwB + ((size_t)(kt_ * 16 + cstep) * 64 + l) * 8);
            d = __builtin_amdgcn_mfma_f32_16x16x32_f16(af, bf, d, 0, 0, 0);
        }
        if (kt_ == 0) {
            sq += __shfl_xor(sq, 16);
            sq += __shfl_xor(sq, 32);
            if (l < 16) xsq[tl * 64 + (ch_ * 2 + m_) * 16 + l] = sq;
        }
        if (wi >= 2)
            *reinterpret_cast<f32x4*>(red + ((tl * 6 + wi - 2) * 64 + l) * 4) = d;
    }
    __syncthreads();   // B1: xsq, red ready (both tiles)

    // ---- softmax (waves wi<2 in each tile group; m = wi) ----
    if (wi < 2) {
        const f32x4 r0 = *reinterpret_cast<const f32x4*>(red + ((tl*6 + wi + 2) * 64 + l) * 4); // (m,kt0,ch1)
        const f32x4 r1 = *reinterpret_cast<const f32x4*>(red + ((tl*6 + wi    ) * 64 + l) * 4); // (m,kt1,ch0)
        const f32x4 r2 = *reinterpret_cast<const f32x4*>(red + ((tl*6 + wi + 4) * 64 + l) * 4); // (m,kt1,ch1)
        const f32x4 d0 = d + r0;
        const f32x4 d1 = r1 + r2;
        const float cq0 = csqL[a],  cq1 = csqL[a + 16];
        const float sf0 = nsfL[a],  sf1 = nsfL[a + 16];
        float wsacc0 = 0.f, wsacc1 = 0.f;
#pragma unroll
        for (int r = 0; r < 4; ++r) {
            const int row = 4 * g + r;
            const float xs = xsq[tl * 64 + (0 * 2 + wi) * 16 + row]
                           + xsq[tl * 64 + (1 * 2 + wi) * 16 + row];
            const float l0 = (xs - 2.f * d0[r] + cq0) * sf0;
            const float l1 = (xs - 2.f * d1[r] + cq1) * sf1;
            const float mx = rowmax16(fmaxf(l0, l1));
            const float e0 = __expf(l0 - mx);
            const float e1 = __expf(l1 - mx);
            const float inv = 1.f / rowsum16(e0 + e1);
            const float w0 = e0 * inv, w1 = e1 * inv;
            wsacc0 += w0; wsacc1 += w1;
            const int n = 16 * wi + row;
            wtT[(size_t)tl * 32 * NP + (a     ) * NP + n] = (f16)w0;
            wtT[(size_t)tl * 32 * NP + (a + 16) * NP + n] = (f16)w1;
        }
        // wsum partials: sum over g groups, store per (tl, m=wi, kt)
        wsacc0 += __shfl_xor(wsacc0, 16); wsacc0 += __shfl_xor(wsacc0, 32);
        wsacc1 += __shfl_xor(wsacc1, 16); wsacc1 += __shfl_xor(wsacc1, 32);
        if (l < 16) {
            wsq[tl * 64 + (wi * 2 + 0) * 16 + l] = wsacc0;
            wsq[tl * 64 + (wi * 2 + 1) * 16 + l] = wsacc1;
        }
    }
    __syncthreads();   // B2: wtT, wsq ready

    // ---- wx MFMA: A from wtT[tl], B direct from global x (f32 -> f16) ----
    {
        const f16* wt = wtT + (size_t)tl * 32 * NP;
        union { f16x8 v; f16x4 h[2]; } A0, A1;
        A0.h[0] = *reinterpret_cast<const f16x4*>(wt + (a     ) * NP + g * 8);
        A0.h[1] = *reinterpret_cast<const f16x4*>(wt + (a     ) * NP + g * 8 + 4);
        A1.h[0] = *reinterpret_cast<const f16x4*>(wt + (a + 16) * NP + g * 8);
        A1.h[1] = *reinterpret_cast<const f16x4*>(wt + (a + 16) * NP + g * 8 + 4);
        const float* xb = x + (size_t)(b * NN + n0 + g * 8) * CCH;
#pragma unroll
        for (int ct = 0; ct < 4; ++ct) {
            const int c = wi * 64 + ct * 16 + a;
            f16x8 B;
#pragma unroll
            for (int i = 0; i < 8; ++i)
                B[i] = (f16)xb[(size_t)i * CCH + c];
            acc[ct][0] = __builtin_amdgcn_mfma_f32_16x16x32_f16(A0.v, B, acc[ct][0], 0, 0, 0);
            acc[ct][1] = __builtin_amdgcn_mfma_f32_16x16x32_f16(A1.v, B, acc[ct][1], 0, 0, 0);
        }
    }
    __syncthreads();   // B3: cwB/red/wtT dead for all waves; wsq ready

    // ---- final wsum store ----
    if (t < 32) {
        const int kt = t >> 4, kk_ = t & 15;
        ws[WS_WSP + ((size_t)blockIdx.x * BB + b) * KK + t] =
              wsq[  0 + (0 * 2 + kt) * 16 + kk_] + wsq[  0 + (1 * 2 + kt) * 16 + kk_]
            + wsq[ 64 + (0 * 2 + kt) * 16 + kk_] + wsq[ 64 + (1 * 2 + kt) * 16 + kk_];
    }

    // ---- epilogue: sum tl pairs via LDS (aliases cwB), stream partials ----
    {
        float* accf = (float*)(sm + LB_ACC);
        float* pp = ws + WS_P + ((size_t)(blockIdx.x * BB + b)) * CCH * KK;
#pragma unroll
        for (int r = 0; r < 2; ++r) {
            if (tl == 1) {
#pragma unroll
                for (int q = 0; q < 2; ++q) {
                    const int ct = 2 * r + q;
#pragma unroll
                    for (int kt = 0; kt < 2; ++kt)
                        *reinterpret_cast<f32x4*>(
                            accf + (((wi * 64 + l) * 2 + q) * 2 + kt) * 4) = acc[ct][kt];
                }
            }
            __syncthreads();
            if (tl == 0) {
#pragma unroll
                for (int q = 0; q < 2; ++q) {
                    const int ct = 2 * r + q;
                    const int c = wi * 64 + ct * 16 + a;
#pragma unroll
                    for (int kt = 0; kt < 2; ++kt) {
                        f32x4 v = *reinterpret_cast<const f32x4*>(
                            accf + (((wi * 64 + l) * 2 + q) * 2 + kt) * 4);
                        v += acc[ct][kt];
                        *reinterpret_cast<f32x4*>(
                            pp + (size_t)c * KK + kt * 16 + g * 4) = v;
                    }
                }
            }
            __syncthreads();
        }
    }
}

// ---------------------------------------------------------------------------
// Kernel R: reduce partials + enc -> BN -> ReLU -> sum_k => encv
// ---------------------------------------------------------------------------
__global__ __launch_bounds__(256) void reduce_encv(
    float* __restrict__ ws, const float* __restrict__ cw,
    const float* __restrict__ gamma, const float* __restrict__ beta,
    const float* __restrict__ mean, const float* __restrict__ var)
{
    __shared__ float wsum_s[KK];
    const int b  = blockIdx.y;
    const int cs = blockIdx.x;
    const int t  = threadIdx.x;

    if (t < KK) {
        float s = 0.f;
        for (int ch = 0; ch < NBLK; ++ch)
            s += ws[WS_WSP + ((size_t)ch * BB + b) * KK + t];
        wsum_s[t] = s;
    }
    __syncthreads();

    const int cl = t >> 3;
    const int c  = cs * 32 + cl;
    const int kq = t & 7;

    float4 aa = make_float4(0.f, 0.f, 0.f, 0.f);
    for (int ch = 0; ch < NBLK; ++ch) {
        const float4 v = *reinterpret_cast<const float4*>(
            ws + WS_P + (((size_t)ch * BB + b) * CCH + c) * KK + kq * 4);
        aa.x += v.x; aa.y += v.y; aa.z += v.z; aa.w += v.w;
    }
    const float g  = gamma[c] * rsqrtf(var[c] + BN_EPS);
    const float mu = mean[c];
    const float be = beta[c];
    const float4 cv = *reinterpret_cast<const float4*>(cw + c * KK + kq * 4);
    const float4 sv = *reinterpret_cast<const float4*>(&wsum_s[kq * 4]);
    float s = 0.f;
    s += fmaxf((aa.x - cv.x * sv.x - mu) * g + be, 0.f);
    s += fmaxf((aa.y - cv.y * sv.y - mu) * g + be, 0.f);
    s += fmaxf((aa.z - cv.z * sv.z - mu) * g + be, 0.f);
    s += fmaxf((aa.w - cv.w * sv.w - mu) * g + be, 0.f);
    s += __shfl_xor(s, 1);
    s += __shfl_xor(s, 2);
    s += __shfl_xor(s, 4);
    if (kq == 0) ws[WS_ENC + (size_t)b * CCH + c] = s;
}

// ---------------------------------------------------------------------------
// Kernel B2: attn = sigmoid(encv @ w_enc + b_enc) ; se = sigmoid(encv @ w_se + b_se)
// ---------------------------------------------------------------------------
__global__ __launch_bounds__(256) void attn_se_kernel(
    const float* __restrict__ enc, float* __restrict__ attn,
    const float* __restrict__ w_enc, const float* __restrict__ b_enc,
    const float* __restrict__ w_se, const float* __restrict__ b_se,
    float* __restrict__ out)
{
    __shared__ float ev[CCH];
    __shared__ float red[4][64];
    const int b   = blockIdx.y;
    const int cgb = blockIdx.x;
    const int t   = threadIdx.x;
    ev[t]       = enc[(size_t)b * CCH + t];
    ev[t + 256] = enc[(size_t)b * CCH + 256 + t];
    __syncthreads();
    if (cgb < 8) {
        const int c2 = cgb * 64 + (t & 63);
        const int p  = t >> 6;
        float a = 0.f;
#pragma unroll 4
        for (int i = 0; i < 128; ++i) {
            const int c = p * 128 + i;
            a += ev[c] * w_enc[c * CCH + c2];
        }
        red[p][t & 63] = a;
        __syncthreads();
        if (t < 64) {
            const float v = red[0][t] + red[1][t] + red[2][t] + red[3][t]
                          + b_enc[cgb * 64 + t];
            attn[(size_t)b * CCH + cgb * 64 + t] = 1.f / (1.f + __expf(-v));
        }
    } else if (t < 8 * CLS) {
        const int j = t >> 3, p = t & 7;
        float a = 0.f;
        for (int c = p; c < CCH; c += 8) a += ev[c] * w_se[c * CLS + j];
        a += __shfl_xor(a, 1);
        a += __shfl_xor(a, 2);
        a += __shfl_xor(a, 4);
        if (p == 0)
            out[(size_t)BB * NN * CCH + b * CLS + j] =
                1.f / (1.f + __expf(-(a + b_se[j])));
    }
}

// ---------------------------------------------------------------------------
// Kernel C: featuremaps = attn[b,c] * x
// ---------------------------------------------------------------------------
__global__ __launch_bounds__(256) void scale_out(
    const float* __restrict__ x, const float* __restrict__ attn,
    float* __restrict__ out)
{
    const int gid = blockIdx.x * 256 + threadIdx.x;
    const int c4  = (gid & 127) << 2;
#pragma unroll
    for (int b = 0; b < BB; ++b) {
        const size_t f = ((size_t)b << 19) + (size_t)gid;
        const float4 xv = *reinterpret_cast<const float4*>(x + 4 * f);
        const float4 av = *reinterpret_cast<const float4*>(attn + (size_t)b * CCH + c4);
        float4 o;
        o.x = xv.x * av.x; o.y = xv.y * av.y; o.z = xv.z * av.z; o.w = xv.w * av.w;
        *reinterpret_cast<float4*>(out + 4 * f) = o;
    }
}

// ---------------------------------------------------------------------------
extern "C" void kernel_launch(void* const* d_in, const int* in_sizes, int n_in,
                              void* d_out, int out_size, void* d_ws, size_t ws_size,
                              hipStream_t stream)
{
    const float* x     = (const float*)d_in[0];
    const float* cw    = (const float*)d_in[1];
    const float* sf    = (const float*)d_in[2];
    const float* gamma = (const float*)d_in[3];
    const float* beta  = (const float*)d_in[4];
    const float* mean  = (const float*)d_in[5];
    const float* var   = (const float*)d_in[6];
    const float* w_enc = (const float*)d_in[7];
    const float* b_enc = (const float*)d_in[8];
    const float* w_se  = (const float*)d_in[9];
    const float* b_se  = (const float*)d_in[10];
    float* out = (float*)d_out;
    float* ws  = (float*)d_ws;

    enc_mfma<<<dim3(NBLK, BB), TPB, LB_TOT, stream>>>(x, cw, sf, ws);
    reduce_encv<<<dim3(16, BB), 256, 0, stream>>>(ws, cw, gamma, beta, mean, var);
    attn_se_kernel<<<dim3(9, BB), 256, 0, stream>>>(
        ws + WS_ENC, ws + WS_ATTN, w_enc, b_enc, w_se, b_se, out);
    scale_out<<<2048, 256, 0, stream>>>(x, ws + WS_ATTN, out);
}